// Round 1
// baseline (782.673 us; speedup 1.0000x reference)
//
#include <hip/hip_runtime.h>
#include <hip/hip_bf16.h>

#define NNODES 50000
#define NEDGES 800000
#define FIN 128
#define FOUT 64
#define TILE_ROWS 64
#define SX_STRIDE 132   // 128 + 4 pad: breaks 32-bank alias for stride-128 row reads

// ---------------------------------------------------------------------------
// Kernel 1: support[r, c] = (sum_k x[r,k] * W[k,c]) * t[r]
// 64-row tile per block, 256 threads as 16x16, each computing a 4x4 micro-tile.
// W (32 KB) + padded X tile (~33 KB) staged in LDS once (K=128 fits fully).
// ---------------------------------------------------------------------------
__global__ __launch_bounds__(256) void gemm_support_kernel(
    const float* __restrict__ x, const float* __restrict__ t,
    const float* __restrict__ W, float* __restrict__ support, int N)
{
    __shared__ float sX[TILE_ROWS * SX_STRIDE];
    __shared__ float sW[FIN * FOUT];

    const int tid  = threadIdx.x;
    const int row0 = blockIdx.x * TILE_ROWS;

    // Stage W: 8192 floats = 2048 float4, 8 per thread, fully coalesced.
    #pragma unroll
    for (int i = 0; i < 8; ++i) {
        int idx = (i * 256 + tid) * 4;
        *(float4*)&sW[idx] = *(const float4*)&W[idx];
    }
    // Stage X tile: 64 rows x 128 cols = 8192 floats, zero-fill past N.
    #pragma unroll
    for (int i = 0; i < 8; ++i) {
        int idx = (i * 256 + tid) * 4;   // flat float index in tile
        int r   = idx >> 7;              // / 128
        int c   = idx & 127;
        float4 v = make_float4(0.f, 0.f, 0.f, 0.f);
        if (row0 + r < N)
            v = *(const float4*)&x[(size_t)(row0 + r) * FIN + c];
        *(float4*)&sX[r * SX_STRIDE + c] = v;
    }
    __syncthreads();

    const int tx = tid & 15;    // col group: cols tx*4 .. tx*4+3
    const int ty = tid >> 4;    // row group: rows ty*4 .. ty*4+3

    float acc[4][4];
    #pragma unroll
    for (int i = 0; i < 4; ++i)
        #pragma unroll
        for (int j = 0; j < 4; ++j)
            acc[i][j] = 0.f;

    #pragma unroll 8
    for (int k = 0; k < FIN; ++k) {
        float4 w = *(float4*)&sW[k * FOUT + tx * 4];
        float xs[4];
        #pragma unroll
        for (int i = 0; i < 4; ++i)
            xs[i] = sX[(ty * 4 + i) * SX_STRIDE + k];
        #pragma unroll
        for (int i = 0; i < 4; ++i) {
            acc[i][0] += xs[i] * w.x;
            acc[i][1] += xs[i] * w.y;
            acc[i][2] += xs[i] * w.z;
            acc[i][3] += xs[i] * w.w;
        }
    }

    #pragma unroll
    for (int i = 0; i < 4; ++i) {
        int r = row0 + ty * 4 + i;
        if (r < N) {
            float tv = t[r];
            float4 o = make_float4(acc[i][0] * tv, acc[i][1] * tv,
                                   acc[i][2] * tv, acc[i][3] * tv);
            *(float4*)&support[(size_t)r * FOUT + tx * 4] = o;
        }
    }
}

// ---------------------------------------------------------------------------
// Kernel 2: out[n, f] = bias[f]   (d_out is poisoned before every launch)
// One float4 per thread.
// ---------------------------------------------------------------------------
__global__ __launch_bounds__(256) void init_out_kernel(
    float* __restrict__ out, const float* __restrict__ bias, int total4)
{
    int i = blockIdx.x * 256 + threadIdx.x;   // float4 index
    if (i < total4) {
        float4 b = *(const float4*)&bias[(i & 15) * 4];
        *(float4*)&out[(size_t)i * 4] = b;
    }
}

// ---------------------------------------------------------------------------
// Kernel 3: for each edge e: out[dst[e], :] += support[src[e], :] * ev[e]
// 16 lanes per edge, each lane handles 4 consecutive features (float4 gather,
// 4 scalar float atomics). support/out are LLC-resident (12.8 MB each).
// ---------------------------------------------------------------------------
__global__ __launch_bounds__(256) void scatter_edges_kernel(
    const int* __restrict__ src, const int* __restrict__ dst,
    const float* __restrict__ ev, const float* __restrict__ support,
    float* __restrict__ out, int E)
{
    int gid  = blockIdx.x * 256 + threadIdx.x;
    int e    = gid >> 4;
    int lane = gid & 15;
    if (e >= E) return;

    int   s = src[e];
    int   d = dst[e];
    float w = ev[e];

    float4 v = *(const float4*)&support[(size_t)s * FOUT + lane * 4];
    float* o = &out[(size_t)d * FOUT + lane * 4];
    atomicAdd(o + 0, v.x * w);
    atomicAdd(o + 1, v.y * w);
    atomicAdd(o + 2, v.z * w);
    atomicAdd(o + 3, v.w * w);
}

extern "C" void kernel_launch(void* const* d_in, const int* in_sizes, int n_in,
                              void* d_out, int out_size, void* d_ws, size_t ws_size,
                              hipStream_t stream) {
    const float* x    = (const float*)d_in[0];   // [N, 128]
    const float* t    = (const float*)d_in[1];   // [N]
    const int*   src  = (const int*)d_in[2];     // [E]
    const int*   dst  = (const int*)d_in[3];     // [E]
    const float* ev   = (const float*)d_in[4];   // [E]
    const float* W    = (const float*)d_in[5];   // [128, 64]
    const float* bias = (const float*)d_in[6];   // [64]
    float* out = (float*)d_out;                  // [N, 64]

    const int N = in_sizes[1];                   // 50000
    const int E = in_sizes[2];                   // 800000

    float* support = (float*)d_ws;               // N*64 floats = 12.8 MB

    // 1) support = (x @ W) * t[:, None]
    int gemm_blocks = (N + TILE_ROWS - 1) / TILE_ROWS;
    gemm_support_kernel<<<gemm_blocks, 256, 0, stream>>>(x, t, W, support, N);

    // 2) out = bias (broadcast)
    int total4 = (N * FOUT) / 4;
    init_out_kernel<<<(total4 + 255) / 256, 256, 0, stream>>>(out, bias, total4);

    // 3) scatter-add edges
    long long sthreads = (long long)E * 16;
    int sblocks = (int)((sthreads + 255) / 256);
    scatter_edges_kernel<<<sblocks, 256, 0, stream>>>(src, dst, ev, support, out, E);
}

// Round 2
// 340.594 us; speedup vs baseline: 2.2980x; 2.2980x over previous
//
#include <hip/hip_runtime.h>
#include <hip/hip_bf16.h>

#define FIN 128
#define FOUT 64
#define TILE_ROWS 64
#define SX_STRIDE 132   // 128 + 4 pad

// Workspace layout (bytes, all 16B-aligned):
//   [0, 12.8e6)            support   : N*64 f32
//   [12,800,000, +200,004) offsets   : (N+1) int  (off[0]=0; off[j+1]=count[j] then scanned)
//   [13,056,000, +200,000) cursor    : N int      (bucket write cursors)
//   [13,312,000, +3.2e6)   src_sorted: E int
//   [16,512,000, +3.2e6)   ev_sorted : E f32
// total ~19.7 MB
#define OFF_OFFSETS 12800000
#define OFF_CURSOR  13056000
#define OFF_SRCS    13312000
#define OFF_EVS     16512000

// ---------------------------------------------------------------------------
// support = (x @ W) * t[:, None]
// ---------------------------------------------------------------------------
__global__ __launch_bounds__(256) void gemm_support_kernel(
    const float* __restrict__ x, const float* __restrict__ t,
    const float* __restrict__ W, float* __restrict__ support, int N)
{
    __shared__ float sX[TILE_ROWS * SX_STRIDE];
    __shared__ float sW[FIN * FOUT];

    const int tid  = threadIdx.x;
    const int row0 = blockIdx.x * TILE_ROWS;

    #pragma unroll
    for (int i = 0; i < 8; ++i) {
        int idx = (i * 256 + tid) * 4;
        *(float4*)&sW[idx] = *(const float4*)&W[idx];
    }
    #pragma unroll
    for (int i = 0; i < 8; ++i) {
        int idx = (i * 256 + tid) * 4;
        int r   = idx >> 7;
        int c   = idx & 127;
        float4 v = make_float4(0.f, 0.f, 0.f, 0.f);
        if (row0 + r < N)
            v = *(const float4*)&x[(size_t)(row0 + r) * FIN + c];
        *(float4*)&sX[r * SX_STRIDE + c] = v;
    }
    __syncthreads();

    const int tx = tid & 15;
    const int ty = tid >> 4;

    float acc[4][4];
    #pragma unroll
    for (int i = 0; i < 4; ++i)
        #pragma unroll
        for (int j = 0; j < 4; ++j)
            acc[i][j] = 0.f;

    #pragma unroll 8
    for (int k = 0; k < FIN; ++k) {
        float4 w = *(float4*)&sW[k * FOUT + tx * 4];
        float xs[4];
        #pragma unroll
        for (int i = 0; i < 4; ++i)
            xs[i] = sX[(ty * 4 + i) * SX_STRIDE + k];
        #pragma unroll
        for (int i = 0; i < 4; ++i) {
            acc[i][0] += xs[i] * w.x;
            acc[i][1] += xs[i] * w.y;
            acc[i][2] += xs[i] * w.z;
            acc[i][3] += xs[i] * w.w;
        }
    }

    #pragma unroll
    for (int i = 0; i < 4; ++i) {
        int r = row0 + ty * 4 + i;
        if (r < N) {
            float tv = t[r];
            float4 o = make_float4(acc[i][0] * tv, acc[i][1] * tv,
                                   acc[i][2] * tv, acc[i][3] * tv);
            *(float4*)&support[(size_t)r * FOUT + tx * 4] = o;
        }
    }
}

// ---------------------------------------------------------------------------
// zero offsets[0..N]
// ---------------------------------------------------------------------------
__global__ __launch_bounds__(256) void zero_offsets_kernel(int* __restrict__ off, int n)
{
    int i = blockIdx.x * 256 + threadIdx.x;
    if (i < n) off[i] = 0;
}

// ---------------------------------------------------------------------------
// histogram: off[dst[e]+1] += 1
// ---------------------------------------------------------------------------
__global__ __launch_bounds__(256) void hist_kernel(
    const int* __restrict__ dst, int* __restrict__ off, int E)
{
    int e = blockIdx.x * 256 + threadIdx.x;
    if (e < E) atomicAdd(&off[dst[e] + 1], 1);
}

// ---------------------------------------------------------------------------
// single-block scan: off[j+1] <- inclusive prefix of counts; cursor[j] <- bucket start
// ---------------------------------------------------------------------------
#define SCAN_THREADS 1024
__global__ __launch_bounds__(SCAN_THREADS) void scan_kernel(
    int* __restrict__ off, int* __restrict__ cursor, int N)
{
    __shared__ int partials[SCAN_THREADS];
    const int tid   = threadIdx.x;
    const int chunk = (N + SCAN_THREADS - 1) / SCAN_THREADS;
    const int lo    = tid * chunk;
    const int hi    = min(lo + chunk, N);

    int sum = 0;
    for (int j = lo; j < hi; ++j) sum += off[j + 1];
    partials[tid] = sum;
    __syncthreads();

    // inclusive Hillis-Steele scan over partials
    for (int d = 1; d < SCAN_THREADS; d <<= 1) {
        int add = (tid >= d) ? partials[tid - d] : 0;
        __syncthreads();
        partials[tid] += add;
        __syncthreads();
    }

    int running = (tid == 0) ? 0 : partials[tid - 1];
    for (int j = lo; j < hi; ++j) {
        cursor[j] = running;          // start of bucket j
        running  += off[j + 1];
        off[j + 1] = running;         // inclusive prefix
    }
}

// ---------------------------------------------------------------------------
// bucket scatter: pos = cursor[dst[e]]++; src_sorted[pos]=src[e]; ev_sorted[pos]=ev[e]
// ---------------------------------------------------------------------------
__global__ __launch_bounds__(256) void build_kernel(
    const int* __restrict__ src, const int* __restrict__ dst,
    const float* __restrict__ ev, int* __restrict__ cursor,
    int* __restrict__ src_sorted, float* __restrict__ ev_sorted, int E)
{
    int e = blockIdx.x * 256 + threadIdx.x;
    if (e >= E) return;
    int d   = dst[e];
    int pos = atomicAdd(&cursor[d], 1);
    src_sorted[pos] = src[e];
    ev_sorted[pos]  = ev[e];
}

// ---------------------------------------------------------------------------
// gather: one wave (64 lanes = 64 features) per node, no atomics.
// ---------------------------------------------------------------------------
__global__ __launch_bounds__(256) void gather_kernel(
    const int* __restrict__ off, const int* __restrict__ srcs,
    const float* __restrict__ evs, const float* __restrict__ support,
    const float* __restrict__ bias, float* __restrict__ out, int N)
{
    int wave = (blockIdx.x * 256 + threadIdx.x) >> 6;
    int lane = threadIdx.x & 63;
    if (wave >= N) return;

    int beg = off[wave];
    int end = off[wave + 1];

    float acc0 = bias[lane];
    float acc1 = 0.f;

    int j = beg;
    for (; j + 1 < end; j += 2) {
        int   s0 = srcs[j];
        int   s1 = srcs[j + 1];
        float w0 = evs[j];
        float w1 = evs[j + 1];
        acc0 += support[(size_t)s0 * FOUT + lane] * w0;
        acc1 += support[(size_t)s1 * FOUT + lane] * w1;
    }
    if (j < end)
        acc0 += support[(size_t)srcs[j] * FOUT + lane] * evs[j];

    out[(size_t)wave * FOUT + lane] = acc0 + acc1;
}

extern "C" void kernel_launch(void* const* d_in, const int* in_sizes, int n_in,
                              void* d_out, int out_size, void* d_ws, size_t ws_size,
                              hipStream_t stream) {
    const float* x    = (const float*)d_in[0];
    const float* t    = (const float*)d_in[1];
    const int*   src  = (const int*)d_in[2];
    const int*   dst  = (const int*)d_in[3];
    const float* ev   = (const float*)d_in[4];
    const float* W    = (const float*)d_in[5];
    const float* bias = (const float*)d_in[6];
    float* out = (float*)d_out;

    const int N = in_sizes[1];   // 50000
    const int E = in_sizes[2];   // 800000

    char* ws = (char*)d_ws;
    float* support    = (float*)ws;
    int*   offsets    = (int*)(ws + OFF_OFFSETS);
    int*   cursor     = (int*)(ws + OFF_CURSOR);
    int*   src_sorted = (int*)(ws + OFF_SRCS);
    float* ev_sorted  = (float*)(ws + OFF_EVS);

    // 1) support = (x @ W) * t[:, None]
    gemm_support_kernel<<<(N + TILE_ROWS - 1) / TILE_ROWS, 256, 0, stream>>>(
        x, t, W, support, N);

    // 2) CSR build: zero -> histogram -> scan -> scatter
    zero_offsets_kernel<<<(N + 1 + 255) / 256, 256, 0, stream>>>(offsets, N + 1);
    hist_kernel<<<(E + 255) / 256, 256, 0, stream>>>(dst, offsets, E);
    scan_kernel<<<1, SCAN_THREADS, 0, stream>>>(offsets, cursor, N);
    build_kernel<<<(E + 255) / 256, 256, 0, stream>>>(
        src, dst, ev, cursor, src_sorted, ev_sorted, E);

    // 3) gather: one wave per node (includes bias)
    long long gthreads = (long long)N * 64;
    gather_kernel<<<(int)((gthreads + 255) / 256), 256, 0, stream>>>(
        offsets, src_sorted, ev_sorted, support, bias, out, N);
}

// Round 3
// 243.473 us; speedup vs baseline: 3.2146x; 1.3989x over previous
//
#include <hip/hip_runtime.h>
#include <hip/hip_bf16.h>

#define FIN 128
#define FOUT 64
#define TILE_ROWS 64
#define SX_STRIDE 132   // 128 + 4 pad

// Workspace layout (bytes, 16B-aligned):
//   [0, 12,800,000)          support      : N*64 f32
//   [12,800,000, 13,000,000) counts/cursor: N int   (hist target, later bucket cursors)
//   [13,000,016, 13,200,032) offsets      : (N+1) int
//   [13,200,032, 13,201,056) blocksums    : 256 int
//   [13,201,056, 16,401,056) src_sorted   : E int
//   [16,401,056, 19,601,056) ev_sorted    : E f32
#define OFF_COUNTS    12800000
#define OFF_OFFSETS   13000016
#define OFF_BLOCKSUMS 13200032
#define OFF_SRCS      13201056
#define OFF_EVS       16401056

#define SCAN_CHUNK 1024   // counts per scan block (256 threads x 4)

// ---------------------------------------------------------------------------
// support = (x @ W) * t[:, None]
// ---------------------------------------------------------------------------
__global__ __launch_bounds__(256) void gemm_support_kernel(
    const float* __restrict__ x, const float* __restrict__ t,
    const float* __restrict__ W, float* __restrict__ support, int N)
{
    __shared__ float sX[TILE_ROWS * SX_STRIDE];
    __shared__ float sW[FIN * FOUT];

    const int tid  = threadIdx.x;
    const int row0 = blockIdx.x * TILE_ROWS;

    #pragma unroll
    for (int i = 0; i < 8; ++i) {
        int idx = (i * 256 + tid) * 4;
        *(float4*)&sW[idx] = *(const float4*)&W[idx];
    }
    #pragma unroll
    for (int i = 0; i < 8; ++i) {
        int idx = (i * 256 + tid) * 4;
        int r   = idx >> 7;
        int c   = idx & 127;
        float4 v = make_float4(0.f, 0.f, 0.f, 0.f);
        if (row0 + r < N)
            v = *(const float4*)&x[(size_t)(row0 + r) * FIN + c];
        *(float4*)&sX[r * SX_STRIDE + c] = v;
    }
    __syncthreads();

    const int tx = tid & 15;
    const int ty = tid >> 4;

    float acc[4][4];
    #pragma unroll
    for (int i = 0; i < 4; ++i)
        #pragma unroll
        for (int j = 0; j < 4; ++j)
            acc[i][j] = 0.f;

    #pragma unroll 8
    for (int k = 0; k < FIN; ++k) {
        float4 w = *(float4*)&sW[k * FOUT + tx * 4];
        float xs[4];
        #pragma unroll
        for (int i = 0; i < 4; ++i)
            xs[i] = sX[(ty * 4 + i) * SX_STRIDE + k];
        #pragma unroll
        for (int i = 0; i < 4; ++i) {
            acc[i][0] += xs[i] * w.x;
            acc[i][1] += xs[i] * w.y;
            acc[i][2] += xs[i] * w.z;
            acc[i][3] += xs[i] * w.w;
        }
    }

    #pragma unroll
    for (int i = 0; i < 4; ++i) {
        int r = row0 + ty * 4 + i;
        if (r < N) {
            float tv = t[r];
            float4 o = make_float4(acc[i][0] * tv, acc[i][1] * tv,
                                   acc[i][2] * tv, acc[i][3] * tv);
            *(float4*)&support[(size_t)r * FOUT + tx * 4] = o;
        }
    }
}

// ---------------------------------------------------------------------------
// counts[0..N) = 0; offsets[0] = 0
// ---------------------------------------------------------------------------
__global__ __launch_bounds__(256) void zero_counts_kernel(
    int* __restrict__ counts, int* __restrict__ off, int N)
{
    int i = blockIdx.x * 256 + threadIdx.x;
    if (i < N) counts[i] = 0;
    if (i == 0) off[0] = 0;
}

// ---------------------------------------------------------------------------
// histogram: counts[dst[e]] += 1
// ---------------------------------------------------------------------------
__global__ __launch_bounds__(256) void hist_kernel(
    const int* __restrict__ dst, int* __restrict__ counts, int E)
{
    int e = blockIdx.x * 256 + threadIdx.x;
    if (e < E) atomicAdd(&counts[dst[e]], 1);
}

// ---------------------------------------------------------------------------
// scan stage 1: per-block sum of SCAN_CHUNK counts -> blocksums[b]
// ---------------------------------------------------------------------------
__global__ __launch_bounds__(256) void scan_sums_kernel(
    const int* __restrict__ counts, int* __restrict__ blocksums, int N)
{
    __shared__ int red[256];
    const int tid  = threadIdx.x;
    const int base = blockIdx.x * SCAN_CHUNK + tid * 4;

    int s = 0;
    if (base + 3 < N) {
        int4 c = *(const int4*)&counts[base];
        s = c.x + c.y + c.z + c.w;
    } else {
        for (int i = 0; i < 4; ++i)
            if (base + i < N) s += counts[base + i];
    }
    red[tid] = s;
    __syncthreads();
    #pragma unroll
    for (int d = 128; d > 0; d >>= 1) {
        if (tid < d) red[tid] += red[tid + d];
        __syncthreads();
    }
    if (tid == 0) blocksums[blockIdx.x] = red[0];
}

// ---------------------------------------------------------------------------
// scan stage 2: one block scans up to 256 block sums -> exclusive offsets
// ---------------------------------------------------------------------------
__global__ __launch_bounds__(256) void scan_block_kernel(
    int* __restrict__ blocksums, int NB)
{
    __shared__ int s[256];
    const int tid = threadIdx.x;
    int v = (tid < NB) ? blocksums[tid] : 0;
    s[tid] = v;
    __syncthreads();
    #pragma unroll
    for (int d = 1; d < 256; d <<= 1) {
        int add = (tid >= d) ? s[tid - d] : 0;
        __syncthreads();
        s[tid] += add;
        __syncthreads();
    }
    if (tid < NB) blocksums[tid] = s[tid] - v;   // exclusive
}

// ---------------------------------------------------------------------------
// scan stage 3: re-read counts, block-local scan + blocksum offset.
// cursor[j] (= counts[j], in place) <- exclusive prefix; off[j+1] <- inclusive.
// In-place is safe: each j is read then written by exactly one thread.
// ---------------------------------------------------------------------------
__global__ __launch_bounds__(256) void scan_apply_kernel(
    int* __restrict__ counts, const int* __restrict__ blocksums,
    int* __restrict__ off, int N)
{
    __shared__ int s[256];
    const int tid  = threadIdx.x;
    const int base = blockIdx.x * SCAN_CHUNK + tid * 4;

    int c[4] = {0, 0, 0, 0};
    if (base + 3 < N) {
        int4 cc = *(const int4*)&counts[base];
        c[0] = cc.x; c[1] = cc.y; c[2] = cc.z; c[3] = cc.w;
    } else {
        for (int i = 0; i < 4; ++i)
            if (base + i < N) c[i] = counts[base + i];
    }
    int mysum = c[0] + c[1] + c[2] + c[3];
    s[tid] = mysum;
    __syncthreads();
    #pragma unroll
    for (int d = 1; d < 256; d <<= 1) {
        int add = (tid >= d) ? s[tid - d] : 0;
        __syncthreads();
        s[tid] += add;
        __syncthreads();
    }
    int ex = blocksums[blockIdx.x] + s[tid] - mysum;   // exclusive prefix at base

    #pragma unroll
    for (int i = 0; i < 4; ++i) {
        if (base + i < N) {
            counts[base + i] = ex;            // cursor = bucket start
            ex += c[i];
            off[base + i + 1] = ex;           // inclusive prefix
        }
    }
}

// ---------------------------------------------------------------------------
// bucket scatter: pos = cursor[dst[e]]++; write src/ev into sorted arrays
// ---------------------------------------------------------------------------
__global__ __launch_bounds__(256) void build_kernel(
    const int* __restrict__ src, const int* __restrict__ dst,
    const float* __restrict__ ev, int* __restrict__ cursor,
    int* __restrict__ src_sorted, float* __restrict__ ev_sorted, int E)
{
    int e = blockIdx.x * 256 + threadIdx.x;
    if (e >= E) return;
    int d   = dst[e];
    int pos = atomicAdd(&cursor[d], 1);
    src_sorted[pos] = src[e];
    ev_sorted[pos]  = ev[e];
}

// ---------------------------------------------------------------------------
// gather: one wave (64 lanes = 64 features) per node, no atomics.
// ---------------------------------------------------------------------------
__global__ __launch_bounds__(256) void gather_kernel(
    const int* __restrict__ off, const int* __restrict__ srcs,
    const float* __restrict__ evs, const float* __restrict__ support,
    const float* __restrict__ bias, float* __restrict__ out, int N)
{
    int wave = (blockIdx.x * 256 + threadIdx.x) >> 6;
    int lane = threadIdx.x & 63;
    if (wave >= N) return;

    int beg = off[wave];
    int end = off[wave + 1];

    float acc0 = bias[lane];
    float acc1 = 0.f;

    int j = beg;
    for (; j + 1 < end; j += 2) {
        int   s0 = srcs[j];
        int   s1 = srcs[j + 1];
        float w0 = evs[j];
        float w1 = evs[j + 1];
        acc0 += support[(size_t)s0 * FOUT + lane] * w0;
        acc1 += support[(size_t)s1 * FOUT + lane] * w1;
    }
    if (j < end)
        acc0 += support[(size_t)srcs[j] * FOUT + lane] * evs[j];

    out[(size_t)wave * FOUT + lane] = acc0 + acc1;
}

extern "C" void kernel_launch(void* const* d_in, const int* in_sizes, int n_in,
                              void* d_out, int out_size, void* d_ws, size_t ws_size,
                              hipStream_t stream) {
    const float* x    = (const float*)d_in[0];
    const float* t    = (const float*)d_in[1];
    const int*   src  = (const int*)d_in[2];
    const int*   dst  = (const int*)d_in[3];
    const float* ev   = (const float*)d_in[4];
    const float* W    = (const float*)d_in[5];
    const float* bias = (const float*)d_in[6];
    float* out = (float*)d_out;

    const int N = in_sizes[1];   // 50000
    const int E = in_sizes[2];   // 800000

    char* ws = (char*)d_ws;
    float* support    = (float*)ws;
    int*   counts     = (int*)(ws + OFF_COUNTS);     // doubles as cursor
    int*   offsets    = (int*)(ws + OFF_OFFSETS);
    int*   blocksums  = (int*)(ws + OFF_BLOCKSUMS);
    int*   src_sorted = (int*)(ws + OFF_SRCS);
    float* ev_sorted  = (float*)(ws + OFF_EVS);

    const int NB = (N + SCAN_CHUNK - 1) / SCAN_CHUNK;   // 49 for N=50000 (<=256 ok)

    // 1) support = (x @ W) * t[:, None]
    gemm_support_kernel<<<(N + TILE_ROWS - 1) / TILE_ROWS, 256, 0, stream>>>(
        x, t, W, support, N);

    // 2) CSR build: zero -> histogram -> hierarchical scan -> bucket scatter
    zero_counts_kernel<<<(N + 255) / 256, 256, 0, stream>>>(counts, offsets, N);
    hist_kernel<<<(E + 255) / 256, 256, 0, stream>>>(dst, counts, E);
    scan_sums_kernel<<<NB, 256, 0, stream>>>(counts, blocksums, N);
    scan_block_kernel<<<1, 256, 0, stream>>>(blocksums, NB);
    scan_apply_kernel<<<NB, 256, 0, stream>>>(counts, blocksums, offsets, N);
    build_kernel<<<(E + 255) / 256, 256, 0, stream>>>(
        src, dst, ev, counts, src_sorted, ev_sorted, E);

    // 3) gather: one wave per node (includes bias)
    long long gthreads = (long long)N * 64;
    gather_kernel<<<(int)((gthreads + 255) / 256), 256, 0, stream>>>(
        offsets, src_sorted, ev_sorted, support, bias, out, N);
}

// Round 4
// 217.954 us; speedup vs baseline: 3.5910x; 1.1171x over previous
//
#include <hip/hip_runtime.h>
#include <hip/hip_bf16.h>

#define FIN 128
#define FOUT 64
#define TILE_ROWS 64
#define SX_STRIDE 132   // 128 + 4 pad

// Workspace layout (bytes):
//   [0, 12,800,000)          support   : N*64 f32
//   [12,800,000, 13,000,000) counts    : N int (hist target, then bucket cursors)
//   [13,000,016, 13,200,032) offsets   : (N+1) int
//   [13,200,032, 13,201,056) blocksums : 256 int
//   [13,201,056, 19,601,056) pairs     : E int2 {src, ev_bits}
#define OFF_COUNTS    12800000
#define OFF_OFFSETS   13000016
#define OFF_BLOCKSUMS 13200032
#define OFF_PAIRS     13201056

#define SCAN_CHUNK 1024   // counts per scan block (256 threads x 4)

// ---------------------------------------------------------------------------
// Fused: blocks [0,GB) compute support = (x@W)*t[:,None]; blocks [GB,..) do
// the dst histogram. Independent work, one dispatch, hist hides under gemm.
// ---------------------------------------------------------------------------
__global__ __launch_bounds__(256) void gemm_hist_kernel(
    const float* __restrict__ x, const float* __restrict__ t,
    const float* __restrict__ W, float* __restrict__ support, int N,
    const int* __restrict__ dst, int* __restrict__ counts, int E, int GB)
{
    __shared__ float sX[TILE_ROWS * SX_STRIDE];
    __shared__ float sW[FIN * FOUT];

    if (blockIdx.x >= GB) {
        int e = (blockIdx.x - GB) * 256 + threadIdx.x;
        if (e < E) atomicAdd(&counts[dst[e]], 1);
        return;
    }

    const int tid  = threadIdx.x;
    const int row0 = blockIdx.x * TILE_ROWS;

    #pragma unroll
    for (int i = 0; i < 8; ++i) {
        int idx = (i * 256 + tid) * 4;
        *(float4*)&sW[idx] = *(const float4*)&W[idx];
    }
    #pragma unroll
    for (int i = 0; i < 8; ++i) {
        int idx = (i * 256 + tid) * 4;
        int r   = idx >> 7;
        int c   = idx & 127;
        float4 v = make_float4(0.f, 0.f, 0.f, 0.f);
        if (row0 + r < N)
            v = *(const float4*)&x[(size_t)(row0 + r) * FIN + c];
        *(float4*)&sX[r * SX_STRIDE + c] = v;
    }
    __syncthreads();

    const int tx = tid & 15;
    const int ty = tid >> 4;

    float acc[4][4];
    #pragma unroll
    for (int i = 0; i < 4; ++i)
        #pragma unroll
        for (int j = 0; j < 4; ++j)
            acc[i][j] = 0.f;

    #pragma unroll 8
    for (int k = 0; k < FIN; ++k) {
        float4 w = *(float4*)&sW[k * FOUT + tx * 4];
        float xs[4];
        #pragma unroll
        for (int i = 0; i < 4; ++i)
            xs[i] = sX[(ty * 4 + i) * SX_STRIDE + k];
        #pragma unroll
        for (int i = 0; i < 4; ++i) {
            acc[i][0] += xs[i] * w.x;
            acc[i][1] += xs[i] * w.y;
            acc[i][2] += xs[i] * w.z;
            acc[i][3] += xs[i] * w.w;
        }
    }

    #pragma unroll
    for (int i = 0; i < 4; ++i) {
        int r = row0 + ty * 4 + i;
        if (r < N) {
            float tv = t[r];
            float4 o = make_float4(acc[i][0] * tv, acc[i][1] * tv,
                                   acc[i][2] * tv, acc[i][3] * tv);
            *(float4*)&support[(size_t)r * FOUT + tx * 4] = o;
        }
    }
}

// ---------------------------------------------------------------------------
// scan stage 1: per-block sum of SCAN_CHUNK counts -> blocksums[b]
// ---------------------------------------------------------------------------
__global__ __launch_bounds__(256) void scan_sums_kernel(
    const int* __restrict__ counts, int* __restrict__ blocksums, int N)
{
    __shared__ int red[256];
    const int tid  = threadIdx.x;
    const int base = blockIdx.x * SCAN_CHUNK + tid * 4;

    int s = 0;
    if (base + 3 < N) {
        int4 c = *(const int4*)&counts[base];
        s = c.x + c.y + c.z + c.w;
    } else {
        for (int i = 0; i < 4; ++i)
            if (base + i < N) s += counts[base + i];
    }
    red[tid] = s;
    __syncthreads();
    #pragma unroll
    for (int d = 128; d > 0; d >>= 1) {
        if (tid < d) red[tid] += red[tid + d];
        __syncthreads();
    }
    if (tid == 0) blocksums[blockIdx.x] = red[0];
}

// ---------------------------------------------------------------------------
// scan stage 2: one block scans up to 256 block sums; also writes off[0]=0
// ---------------------------------------------------------------------------
__global__ __launch_bounds__(256) void scan_block_kernel(
    int* __restrict__ blocksums, int* __restrict__ off, int NB)
{
    __shared__ int s[256];
    const int tid = threadIdx.x;
    if (tid == 255) off[0] = 0;
    int v = (tid < NB) ? blocksums[tid] : 0;
    s[tid] = v;
    __syncthreads();
    #pragma unroll
    for (int d = 1; d < 256; d <<= 1) {
        int add = (tid >= d) ? s[tid - d] : 0;
        __syncthreads();
        s[tid] += add;
        __syncthreads();
    }
    if (tid < NB) blocksums[tid] = s[tid] - v;   // exclusive
}

// ---------------------------------------------------------------------------
// scan stage 3: counts[j] <- exclusive prefix (cursor); off[j+1] <- inclusive
// ---------------------------------------------------------------------------
__global__ __launch_bounds__(256) void scan_apply_kernel(
    int* __restrict__ counts, const int* __restrict__ blocksums,
    int* __restrict__ off, int N)
{
    __shared__ int s[256];
    const int tid  = threadIdx.x;
    const int base = blockIdx.x * SCAN_CHUNK + tid * 4;

    int c[4] = {0, 0, 0, 0};
    if (base + 3 < N) {
        int4 cc = *(const int4*)&counts[base];
        c[0] = cc.x; c[1] = cc.y; c[2] = cc.z; c[3] = cc.w;
    } else {
        for (int i = 0; i < 4; ++i)
            if (base + i < N) c[i] = counts[base + i];
    }
    int mysum = c[0] + c[1] + c[2] + c[3];
    s[tid] = mysum;
    __syncthreads();
    #pragma unroll
    for (int d = 1; d < 256; d <<= 1) {
        int add = (tid >= d) ? s[tid - d] : 0;
        __syncthreads();
        s[tid] += add;
        __syncthreads();
    }
    int ex = blocksums[blockIdx.x] + s[tid] - mysum;

    #pragma unroll
    for (int i = 0; i < 4; ++i) {
        if (base + i < N) {
            counts[base + i] = ex;            // cursor = bucket start
            ex += c[i];
            off[base + i + 1] = ex;           // inclusive prefix
        }
    }
}

// ---------------------------------------------------------------------------
// bucket scatter: one packed 8B store per edge
// ---------------------------------------------------------------------------
__global__ __launch_bounds__(256) void build_kernel(
    const int* __restrict__ src, const int* __restrict__ dst,
    const float* __restrict__ ev, int* __restrict__ cursor,
    int2* __restrict__ pairs, int E)
{
    int e = blockIdx.x * 256 + threadIdx.x;
    if (e >= E) return;
    int d   = dst[e];
    int pos = atomicAdd(&cursor[d], 1);
    pairs[pos] = make_int2(src[e], __float_as_int(ev[e]));
}

// ---------------------------------------------------------------------------
// gather: one wave per node. Preload up to 64 edge-pairs coalesced, then
// shuffle-broadcast each edge; support row loads issue back-to-back.
// ---------------------------------------------------------------------------
__global__ __launch_bounds__(256) void gather_kernel(
    const int* __restrict__ off, const int2* __restrict__ pairs,
    const float* __restrict__ support, const float* __restrict__ bias,
    float* __restrict__ out, int N)
{
    int wave = (blockIdx.x * 256 + threadIdx.x) >> 6;
    int lane = threadIdx.x & 63;
    if (wave >= N) return;

    int beg = off[wave];
    int end = off[wave + 1];

    float acc0 = bias[lane];
    float acc1 = 0.f;

    for (int base = beg; base < end; base += 64) {
        int cnt = min(64, end - base);
        int2 p = make_int2(0, 0);
        if (base + lane < end) p = pairs[base + lane];

        int i = 0;
        for (; i + 1 < cnt; i += 2) {
            int   s0 = __shfl(p.x, i);
            float w0 = __int_as_float(__shfl(p.y, i));
            int   s1 = __shfl(p.x, i + 1);
            float w1 = __int_as_float(__shfl(p.y, i + 1));
            float v0 = support[(size_t)s0 * FOUT + lane];
            float v1 = support[(size_t)s1 * FOUT + lane];
            acc0 += v0 * w0;
            acc1 += v1 * w1;
        }
        if (i < cnt) {
            int   s0 = __shfl(p.x, i);
            float w0 = __int_as_float(__shfl(p.y, i));
            acc0 += support[(size_t)s0 * FOUT + lane] * w0;
        }
    }

    out[(size_t)wave * FOUT + lane] = acc0 + acc1;
}

extern "C" void kernel_launch(void* const* d_in, const int* in_sizes, int n_in,
                              void* d_out, int out_size, void* d_ws, size_t ws_size,
                              hipStream_t stream) {
    const float* x    = (const float*)d_in[0];
    const float* t    = (const float*)d_in[1];
    const int*   src  = (const int*)d_in[2];
    const int*   dst  = (const int*)d_in[3];
    const float* ev   = (const float*)d_in[4];
    const float* W    = (const float*)d_in[5];
    const float* bias = (const float*)d_in[6];
    float* out = (float*)d_out;

    const int N = in_sizes[1];   // 50000
    const int E = in_sizes[2];   // 800000

    char* ws = (char*)d_ws;
    float* support   = (float*)ws;
    int*   counts    = (int*)(ws + OFF_COUNTS);    // doubles as cursor
    int*   offsets   = (int*)(ws + OFF_OFFSETS);
    int*   blocksums = (int*)(ws + OFF_BLOCKSUMS);
    int2*  pairs     = (int2*)(ws + OFF_PAIRS);

    const int GB = (N + TILE_ROWS - 1) / TILE_ROWS;     // gemm blocks (782)
    const int HB = (E + 255) / 256;                     // hist blocks (3125)
    const int NB = (N + SCAN_CHUNK - 1) / SCAN_CHUNK;   // scan blocks (49)

    // 0) counts = 0 (graph-capturable async memset)
    hipMemsetAsync(counts, 0, (size_t)N * sizeof(int), stream);

    // 1) fused gemm + histogram
    gemm_hist_kernel<<<GB + HB, 256, 0, stream>>>(
        x, t, W, support, N, dst, counts, E, GB);

    // 2) hierarchical scan -> offsets + cursors
    scan_sums_kernel<<<NB, 256, 0, stream>>>(counts, blocksums, N);
    scan_block_kernel<<<1, 256, 0, stream>>>(blocksums, offsets, NB);
    scan_apply_kernel<<<NB, 256, 0, stream>>>(counts, blocksums, offsets, N);

    // 3) bucket scatter (packed 8B per edge)
    build_kernel<<<HB, 256, 0, stream>>>(src, dst, ev, counts, pairs, E);

    // 4) gather: one wave per node (includes bias)
    long long gthreads = (long long)N * 64;
    gather_kernel<<<(int)((gthreads + 255) / 256), 256, 0, stream>>>(
        offsets, pairs, support, bias, out, N);
}

// Round 6
// 168.859 us; speedup vs baseline: 4.6351x; 1.2907x over previous
//
#include <hip/hip_runtime.h>
#include <hip/hip_bf16.h>

#define FIN 128
#define FOUT 64
#define TILE_ROWS 64
#define SX_STRIDE 132      // 128 + 4 pad

#define EPB 4096           // edges per sort block
#define NPB 128            // nodes per coarse bucket (d >> 7)
#define NBUK_MAX 512

// Workspace layout (bytes, 16B-aligned):
//   [0, 6,400,000)           support   : N*64 bf16
//   [6,400,000, +306,544)    hist      : NBUK*SB int (bucket-major [B][b])
//   [6,706,560, +200,004)    offsets   : (N+1) int
//   [6,906,576, +1,024)      blocksums : 256 int
//   [6,907,600, +6,400,000)  tmp       : E int2 {src16 | dnode<<16, ev}
//   [13,307,600, +6,400,000) pairs     : E int2 {src, ev}
#define OFF_HIST      6400000
#define OFF_OFFSETS   6706560
#define OFF_BLOCKSUMS 6906576
#define OFF_TMP       6907600
#define OFF_PAIRS     13307600

#define SCAN_CHUNK 1024

// f32 -> bf16 with round-to-nearest-even (bit-level, no type-API dependency)
__device__ inline ushort f32_to_bf16_rne(float f) {
    unsigned u = __float_as_uint(f);
    u += 0x7FFFu + ((u >> 16) & 1u);
    return (ushort)(u >> 16);
}

// ---------------------------------------------------------------------------
// support(bf16) = (x @ W) * t[:,None].  W read through L1 (32 KB, shared by
// all blocks); only the X tile is LDS-staged -> 34 KB LDS -> 4 blocks/CU.
// ---------------------------------------------------------------------------
__global__ __launch_bounds__(256) void gemm_kernel(
    const float* __restrict__ x, const float* __restrict__ t,
    const float* __restrict__ W, ushort* __restrict__ support, int N)
{
    __shared__ float sX[TILE_ROWS * SX_STRIDE];

    const int tid  = threadIdx.x;
    const int row0 = blockIdx.x * TILE_ROWS;

    #pragma unroll
    for (int i = 0; i < 8; ++i) {
        int idx = (i * 256 + tid) * 4;
        int r   = idx >> 7;
        int c   = idx & 127;
        float4 v = make_float4(0.f, 0.f, 0.f, 0.f);
        if (row0 + r < N)
            v = *(const float4*)&x[(size_t)(row0 + r) * FIN + c];
        *(float4*)&sX[r * SX_STRIDE + c] = v;
    }
    __syncthreads();

    const int tx = tid & 15;
    const int ty = tid >> 4;

    float acc[4][4];
    #pragma unroll
    for (int i = 0; i < 4; ++i)
        #pragma unroll
        for (int j = 0; j < 4; ++j)
            acc[i][j] = 0.f;

    #pragma unroll 8
    for (int k = 0; k < FIN; ++k) {
        float4 w = *(const float4*)&W[k * FOUT + tx * 4];   // L1-resident
        float xs[4];
        #pragma unroll
        for (int i = 0; i < 4; ++i)
            xs[i] = sX[(ty * 4 + i) * SX_STRIDE + k];
        #pragma unroll
        for (int i = 0; i < 4; ++i) {
            acc[i][0] += xs[i] * w.x;
            acc[i][1] += xs[i] * w.y;
            acc[i][2] += xs[i] * w.z;
            acc[i][3] += xs[i] * w.w;
        }
    }

    #pragma unroll
    for (int i = 0; i < 4; ++i) {
        int r = row0 + ty * 4 + i;
        if (r < N) {
            float tv = t[r];
            ushort4 o;
            o.x = f32_to_bf16_rne(acc[i][0] * tv);
            o.y = f32_to_bf16_rne(acc[i][1] * tv);
            o.z = f32_to_bf16_rne(acc[i][2] * tv);
            o.w = f32_to_bf16_rne(acc[i][3] * tv);
            *(ushort4*)&support[(size_t)r * FOUT + tx * 4] = o;
        }
    }
}

// ---------------------------------------------------------------------------
// K0: per-block coarse histogram over NBUK buckets -> hist[b*SB + B]
// ---------------------------------------------------------------------------
__global__ __launch_bounds__(256) void coarse_hist_kernel(
    const int* __restrict__ dst, int* __restrict__ hist,
    int E, int SB, int NBUK)
{
    __shared__ int h[NBUK_MAX];
    const int tid = threadIdx.x;
    for (int i = tid; i < NBUK; i += 256) h[i] = 0;
    __syncthreads();

    const int e0 = blockIdx.x * EPB;
    for (int i = tid; i < EPB; i += 256) {
        int e = e0 + i;
        if (e < E) atomicAdd(&h[dst[e] >> 7], 1);
    }
    __syncthreads();
    for (int i = tid; i < NBUK; i += 256)
        hist[i * SB + blockIdx.x] = h[i];
}

// ---------------------------------------------------------------------------
// scan stage 1: per-block sums of SCAN_CHUNK elements
// ---------------------------------------------------------------------------
__global__ __launch_bounds__(256) void scan_sums_kernel(
    const int* __restrict__ counts, int* __restrict__ blocksums, int M)
{
    __shared__ int red[256];
    const int tid  = threadIdx.x;
    const int base = blockIdx.x * SCAN_CHUNK + tid * 4;

    int s = 0;
    if (base + 3 < M) {
        int4 c = *(const int4*)&counts[base];
        s = c.x + c.y + c.z + c.w;
    } else {
        for (int i = 0; i < 4; ++i)
            if (base + i < M) s += counts[base + i];
    }
    red[tid] = s;
    __syncthreads();
    #pragma unroll
    for (int d = 128; d > 0; d >>= 1) {
        if (tid < d) red[tid] += red[tid + d];
        __syncthreads();
    }
    if (tid == 0) blocksums[blockIdx.x] = red[0];
}

// ---------------------------------------------------------------------------
// scan stage 2: one block scans <=256 block sums -> exclusive
// ---------------------------------------------------------------------------
__global__ __launch_bounds__(256) void scan_block_kernel(
    int* __restrict__ blocksums, int NB)
{
    __shared__ int s[256];
    const int tid = threadIdx.x;
    int v = (tid < NB) ? blocksums[tid] : 0;
    s[tid] = v;
    __syncthreads();
    #pragma unroll
    for (int d = 1; d < 256; d <<= 1) {
        int add = (tid >= d) ? s[tid - d] : 0;
        __syncthreads();
        s[tid] += add;
        __syncthreads();
    }
    if (tid < NB) blocksums[tid] = s[tid] - v;
}

// ---------------------------------------------------------------------------
// scan stage 3: counts[j] <- exclusive prefix, in place
// ---------------------------------------------------------------------------
__global__ __launch_bounds__(256) void scan_apply_excl_kernel(
    int* __restrict__ counts, const int* __restrict__ blocksums, int M)
{
    __shared__ int s[256];
    const int tid  = threadIdx.x;
    const int base = blockIdx.x * SCAN_CHUNK + tid * 4;

    int c[4] = {0, 0, 0, 0};
    if (base + 3 < M) {
        int4 cc = *(const int4*)&counts[base];
        c[0] = cc.x; c[1] = cc.y; c[2] = cc.z; c[3] = cc.w;
    } else {
        for (int i = 0; i < 4; ++i)
            if (base + i < M) c[i] = counts[base + i];
    }
    int mysum = c[0] + c[1] + c[2] + c[3];
    s[tid] = mysum;
    __syncthreads();
    #pragma unroll
    for (int d = 1; d < 256; d <<= 1) {
        int add = (tid >= d) ? s[tid - d] : 0;
        __syncthreads();
        s[tid] += add;
        __syncthreads();
    }
    int ex = blocksums[blockIdx.x] + s[tid] - mysum;
    #pragma unroll
    for (int i = 0; i < 4; ++i) {
        if (base + i < M) {
            counts[base + i] = ex;
            ex += c[i];
        }
    }
}

// ---------------------------------------------------------------------------
// K2: coarse scatter. Private per-(block,bucket) cursors (LDS atomics only).
// rec = {src | (d&127)<<16, ev_bits}
// ---------------------------------------------------------------------------
__global__ __launch_bounds__(256) void coarse_scatter_kernel(
    const int* __restrict__ src, const int* __restrict__ dst,
    const float* __restrict__ ev, const int* __restrict__ scanned,
    int2* __restrict__ tmp, int E, int SB, int NBUK)
{
    __shared__ int cur[NBUK_MAX];
    const int tid = threadIdx.x;
    for (int i = tid; i < NBUK; i += 256)
        cur[i] = scanned[i * SB + blockIdx.x];
    __syncthreads();

    const int e0 = blockIdx.x * EPB;
    for (int i = tid; i < EPB; i += 256) {
        int e = e0 + i;
        if (e < E) {
            int d   = dst[e];
            int pos = atomicAdd(&cur[d >> 7], 1);
            tmp[pos] = make_int2(src[e] | ((d & (NPB - 1)) << 16),
                                 __float_as_int(ev[e]));
        }
    }
}

// ---------------------------------------------------------------------------
// K3: fine sort within one coarse bucket (one block per bucket, single-writer
// output region). Emits off[] and final pairs {src, ev_bits}.
// ---------------------------------------------------------------------------
__global__ __launch_bounds__(256) void fine_sort_kernel(
    const int* __restrict__ scanned, const int2* __restrict__ tmp,
    int2* __restrict__ pairs, int* __restrict__ off,
    int E, int N, int SB, int NBUK)
{
    __shared__ int fcnt[NPB];
    __shared__ int fcur[NPB];
    const int tid = threadIdx.x;
    const int B   = blockIdx.x;

    const int base = scanned[B * SB];
    const int endB = (B + 1 < NBUK) ? scanned[(B + 1) * SB] : E;

    if (tid < NPB) fcnt[tid] = 0;
    __syncthreads();

    for (int i = base + tid; i < endB; i += 256)
        atomicAdd(&fcnt[(tmp[i].x >> 16) & (NPB - 1)], 1);
    __syncthreads();

    // inclusive Hillis-Steele over NPB=128 counters
    if (tid < NPB) fcur[tid] = fcnt[tid];
    __syncthreads();
    #pragma unroll
    for (int d = 1; d < NPB; d <<= 1) {
        int v = (tid < NPB && tid >= d) ? fcur[tid - d] : 0;
        __syncthreads();
        if (tid < NPB) fcur[tid] += v;
        __syncthreads();
    }
    if (tid < NPB) {
        int start = base + fcur[tid] - fcnt[tid];   // exclusive
        int node  = B * NPB + tid;
        fcur[tid] = start;
        if (node < N) off[node] = start;
    }
    if (B == 0 && tid == 0) off[N] = E;
    __syncthreads();

    for (int i = base + tid; i < endB; i += 256) {
        int2 r  = tmp[i];
        int pos = atomicAdd(&fcur[(r.x >> 16) & (NPB - 1)], 1);
        pairs[pos] = make_int2(r.x & 0xFFFF, r.y);
    }
}

// ---------------------------------------------------------------------------
// gather: one wave per node; bf16 support rows; shfl-broadcast edge pairs.
// ---------------------------------------------------------------------------
__global__ __launch_bounds__(256) void gather_kernel(
    const int* __restrict__ off, const int2* __restrict__ pairs,
    const ushort* __restrict__ support, const float* __restrict__ bias,
    float* __restrict__ out, int N)
{
    int wave = (blockIdx.x * 256 + threadIdx.x) >> 6;
    int lane = threadIdx.x & 63;
    if (wave >= N) return;

    int beg = off[wave];
    int end = off[wave + 1];

    float acc0 = bias[lane];
    float acc1 = 0.f;

    for (int base = beg; base < end; base += 64) {
        int cnt = min(64, end - base);
        int2 p = make_int2(0, 0);
        if (base + lane < end) p = pairs[base + lane];

        int i = 0;
        for (; i + 1 < cnt; i += 2) {
            int   s0 = __shfl(p.x, i);
            float w0 = __int_as_float(__shfl(p.y, i));
            int   s1 = __shfl(p.x, i + 1);
            float w1 = __int_as_float(__shfl(p.y, i + 1));
            float v0 = __uint_as_float((unsigned)support[(size_t)s0 * FOUT + lane] << 16);
            float v1 = __uint_as_float((unsigned)support[(size_t)s1 * FOUT + lane] << 16);
            acc0 += v0 * w0;
            acc1 += v1 * w1;
        }
        if (i < cnt) {
            int   s0 = __shfl(p.x, i);
            float w0 = __int_as_float(__shfl(p.y, i));
            float v0 = __uint_as_float((unsigned)support[(size_t)s0 * FOUT + lane] << 16);
            acc0 += v0 * w0;
        }
    }

    out[(size_t)wave * FOUT + lane] = acc0 + acc1;
}

extern "C" void kernel_launch(void* const* d_in, const int* in_sizes, int n_in,
                              void* d_out, int out_size, void* d_ws, size_t ws_size,
                              hipStream_t stream) {
    const float* x    = (const float*)d_in[0];
    const float* t    = (const float*)d_in[1];
    const int*   src  = (const int*)d_in[2];
    const int*   dst  = (const int*)d_in[3];
    const float* ev   = (const float*)d_in[4];
    const float* W    = (const float*)d_in[5];
    const float* bias = (const float*)d_in[6];
    float* out = (float*)d_out;

    const int N = in_sizes[1];   // 50000
    const int E = in_sizes[2];   // 800000

    char*   ws        = (char*)d_ws;
    ushort* support   = (ushort*)ws;
    int*    hist      = (int*)(ws + OFF_HIST);
    int*    offsets   = (int*)(ws + OFF_OFFSETS);
    int*    blocksums = (int*)(ws + OFF_BLOCKSUMS);
    int2*   tmp       = (int2*)(ws + OFF_TMP);
    int2*   pairs     = (int2*)(ws + OFF_PAIRS);

    const int SB   = (E + EPB - 1) / EPB;          // 196 sort blocks
    const int NBUK = (N + NPB - 1) / NPB;          // 391 coarse buckets
    const int M    = NBUK * SB;                    // 76,636 hist entries
    const int NBS  = (M + SCAN_CHUNK - 1) / SCAN_CHUNK;  // 75 scan blocks

    // 1) support = bf16((x @ W) * t[:,None])
    gemm_kernel<<<(N + TILE_ROWS - 1) / TILE_ROWS, 256, 0, stream>>>(
        x, t, W, support, N);

    // 2) two-level counting sort of edges by dst
    coarse_hist_kernel<<<SB, 256, 0, stream>>>(dst, hist, E, SB, NBUK);
    scan_sums_kernel<<<NBS, 256, 0, stream>>>(hist, blocksums, M);
    scan_block_kernel<<<1, 256, 0, stream>>>(blocksums, NBS);
    scan_apply_excl_kernel<<<NBS, 256, 0, stream>>>(hist, blocksums, M);
    coarse_scatter_kernel<<<SB, 256, 0, stream>>>(
        src, dst, ev, hist, tmp, E, SB, NBUK);
    fine_sort_kernel<<<NBUK, 256, 0, stream>>>(
        hist, tmp, pairs, offsets, E, N, SB, NBUK);

    // 3) gather: one wave per node (includes bias)
    long long gthreads = (long long)N * 64;
    gather_kernel<<<(int)((gthreads + 255) / 256), 256, 0, stream>>>(
        offsets, pairs, support, bias, out, N);
}